// Round 1
// baseline (255.024 us; speedup 1.0000x reference)
//
#include <hip/hip_runtime.h>

typedef unsigned short u16;
typedef __bf16 bf16x8 __attribute__((ext_vector_type(8)));
typedef float floatx4 __attribute__((ext_vector_type(4)));

#define B_ 4
#define SEQ 2048
#define DIM 1024

__device__ __forceinline__ u16 f2bf(float f) {
    unsigned u = __builtin_bit_cast(unsigned, f);
    u += 0x7FFFu + ((u >> 16) & 1u);
    return (u16)(u >> 16);
}
__device__ __forceinline__ float bf2f(u16 h) {
    unsigned u = ((unsigned)h) << 16;
    return __builtin_bit_cast(float, u);
}

#define GPTR(p) ((const __attribute__((address_space(1))) void*)(p))
#define LPTR(p) ((__attribute__((address_space(3))) void*)(p))
#define GLD(src, dstp) __builtin_amdgcn_global_load_lds(GPTR(src), LPTR(dstp), 16, 0, 0)

// ---------------- convert x fp32 -> bf16 ----------------
__global__ __launch_bounds__(256) void convert_x(const float4* __restrict__ x,
                                                 ushort4* __restrict__ xb) {
    int i = blockIdx.x * 256 + threadIdx.x;  // 2M float4s
    float4 v = x[i];
    ushort4 o;
    o.x = f2bf(v.x); o.y = f2bf(v.y); o.z = f2bf(v.z); o.w = f2bf(v.w);
    xb[i] = o;
}

// ---------------- transpose W [k][n] fp32 -> Wt [n][k] bf16 ----------------
__global__ __launch_bounds__(256) void transpose_w(const float* __restrict__ Wq,
                                                   const float* __restrict__ Wk,
                                                   const float* __restrict__ Wv,
                                                   u16* __restrict__ Wt) {
    __shared__ u16 t[64][66];
    const int z = blockIdx.z;
    const float* W = (z == 0) ? Wq : ((z == 1) ? Wk : Wv);
    u16* out = Wt + (size_t)z * DIM * DIM;
    const int tx = threadIdx.x, ty = threadIdx.y;  // (32,8)
    const int k0 = blockIdx.x * 64, n0 = blockIdx.y * 64;
#pragma unroll
    for (int j = 0; j < 8; j++) {
        int k = ty + 8 * j;
        float2 v = *(const float2*)(W + (size_t)(k0 + k) * DIM + n0 + 2 * tx);
        t[2 * tx][k] = f2bf(v.x);
        t[2 * tx + 1][k] = f2bf(v.y);
    }
    __syncthreads();
#pragma unroll
    for (int j = 0; j < 8; j++) {
        int n = ty + 8 * j;
        ushort2 o;
        o.x = t[n][2 * tx];
        o.y = t[n][2 * tx + 1];
        *(ushort2*)(out + (size_t)(n0 + n) * DIM + k0 + 2 * tx) = o;
    }
}

// ---- 128x128 bf16 MFMA mainloop (unchanged; still used by scores/pv) ------
__device__ __forceinline__ void mainloop(
    const u16* __restrict__ Ab, const u16* __restrict__ Bb, int lda, int ldb,
    int Kt, u16* lsA, u16* lsB, int tid, int wave, int quad, int l15,
    int wm, int wn, floatx4 (&acc)[4][4]) {
    const int srow = tid >> 2;                                // 0..63
    const int scol = ((tid & 3) ^ ((tid >> 3) & 3)) * 8;      // swizzled kseg
    const u16* gA = Ab + (size_t)srow * lda + scol;
    const u16* gB = Bb + (size_t)srow * ldb + scol;
    const int swq = (quad ^ ((l15 >> 1) & 3)) * 8;            // read-side xor

#pragma unroll
    for (int i = 0; i < 4; i++)
#pragma unroll
        for (int j = 0; j < 4; j++) {
            floatx4 zz = {0.f, 0.f, 0.f, 0.f};
            acc[i][j] = zz;
        }

    for (int k0 = 0; k0 < Kt; k0 += 64) {
#pragma unroll
        for (int h = 0; h < 2; h++)
#pragma unroll
            for (int c = 0; c < 2; c++) {
                __builtin_amdgcn_global_load_lds(
                    GPTR(gA + (size_t)c * 64 * lda + h * 32),
                    LPTR(lsA + h * 4096 + c * 2048 + wave * 512), 16, 0, 0);
                __builtin_amdgcn_global_load_lds(
                    GPTR(gB + (size_t)c * 64 * ldb + h * 32),
                    LPTR(lsB + h * 4096 + c * 2048 + wave * 512), 16, 0, 0);
            }
        gA += 64; gB += 64;
        __syncthreads();

#pragma unroll
        for (int h = 0; h < 2; h++) {
            bf16x8 af[4];
#pragma unroll
            for (int i = 0; i < 4; i++)
                af[i] = *(const bf16x8*)(lsA + h * 4096 + (wm + i * 16 + l15) * 32 + swq);
#pragma unroll
            for (int j = 0; j < 4; j++) {
                bf16x8 bfr = *(const bf16x8*)(lsB + h * 4096 + (wn + j * 16 + l15) * 32 + swq);
#pragma unroll
                for (int i = 0; i < 4; i++)
                    acc[i][j] = __builtin_amdgcn_mfma_f32_16x16x32_bf16(af[i], bfr, acc[i][j], 0, 0, 0);
            }
        }
        __syncthreads();
    }
}

// ================= QKV projection: 256x256 tile, 8-wave, 4-phase ============
// counted-vmcnt schedule (T3+T4+T5).  A [8192][1024], B=Wt [3072][1024], both
// row-major-over-k.  512 thr = 8 waves (2M x 4N), per-wave 128x64 output,
// M_rep=8 N_rep=4, B-frags held in regs over the whole K-tile (halves LDS BW).
// LDS 128 KiB = 2 dbuf x (A 32KB + B 32KB), layout per tensor:
//   [H(128-row half)][c(64-row)][s(ksplit 32)][64][32] with the R6-proven
//   slot swizzle: seg slot = ks ^ ((row>>1)&3)  (2-way conflict = free).
// Per K-tile: 8 gload_lds/thread in order [B00 B01 | B10 B11 | A00 A10 | A01 A11],
// 2 per phase, staged one tile ahead.  Phase entry waits (derived, never 0 in
// steady state):  p0 vmcnt(2), p1 vmcnt(4), p2 vmcnt(4), p3 vmcnt(6).
//   p0 needs tile-t B(all)+A(*,0) = issues older than last 2   -> 2
//   p2 needs tile-t A(*,1) = issues older than last 4 (p0,p1)  -> 4
// Last tile has no newer issues so its p2 must drain: vmcnt(0).
__global__ __launch_bounds__(512, 2) void gemm_qkv256(
    const u16* __restrict__ A, const u16* __restrict__ Bt, u16* __restrict__ QK,
    const float* __restrict__ b0, const float* __restrict__ b1, const float* __restrict__ b2,
    u16* __restrict__ VtOut) {
    __shared__ union {
        u16 stage[2][32768];   // [dbuf][A:16384 | B:16384]  (128 KiB)
        u16 T[65536];          // V^T epilogue transpose (128 KiB)
    } sm;
    u16* lsbase = &sm.stage[0][0];

    const int tid = threadIdx.x;
    const int wave = tid >> 6, lane = tid & 63;
    const int quad = lane >> 4, l15 = lane & 15;
    const int wmH = wave >> 2;          // 0..1  : A half (128 rows)
    const int wnI = wave & 3;           // 0..3  : 64-col slot
    const int swq = (quad ^ ((l15 >> 1) & 3)) * 8;
    const int rdoff = l15 * 32 + swq;

    // XCD-bijective swizzle (384 = 8*48), mt-fast for B-panel L2 reuse
    const int bid = blockIdx.x;
    const int wgid = (bid & 7) * 48 + (bid >> 3);
    const int mt = wgid & 31, nt = wgid >> 5;   // 32 M-tiles x 12 N-tiles

    // staging source: thread t covers (s=t>>8, row=(t&255)>>2, slot=t&3)
    const int rl = (tid & 255) >> 2;
    const int sS = tid >> 8;
    const int sseg = ((tid & 3) ^ ((tid >> 3) & 3)) * 8;
    const u16* sA = A + (size_t)mt * 256 * DIM + (size_t)rl * DIM + sS * 32 + sseg;
    const u16* sB = Bt + (size_t)nt * 256 * DIM + (size_t)rl * DIM + sS * 32 + sseg;

    // ---- prologue: stage tile 0 into buf 0 (order matches vmcnt math) ----
    {
        u16* An0 = lsbase;
        u16* Bn0 = lsbase + 16384;
        GLD(sB,                      Bn0 + 0     + wave * 512);
        GLD(sB + (size_t)64  * DIM,  Bn0 + 4096  + wave * 512);
        GLD(sB + (size_t)128 * DIM,  Bn0 + 8192  + wave * 512);
        GLD(sB + (size_t)192 * DIM,  Bn0 + 12288 + wave * 512);
        GLD(sA,                      An0 + 0     + wave * 512);
        GLD(sA + (size_t)128 * DIM,  An0 + 8192  + wave * 512);
        GLD(sA + (size_t)64  * DIM,  An0 + 4096  + wave * 512);
        GLD(sA + (size_t)192 * DIM,  An0 + 12288 + wave * 512);
    }
    const u16* sAk = sA + 64;   // next tile to stage
    const u16* sBk = sB + 64;

    floatx4 acc[8][4];
#pragma unroll
    for (int i = 0; i < 8; i++)
#pragma unroll
        for (int j = 0; j < 4; j++) {
            floatx4 zz = {0.f, 0.f, 0.f, 0.f};
            acc[i][j] = zz;
        }

    const int NT = DIM / 64;  // 16
#pragma unroll 2
    for (int t = 0; t < NT; ++t) {
        const u16* Ac = lsbase + (t & 1) * 32768 + wmH * 8192;
        const u16* Bc = lsbase + (t & 1) * 32768 + 16384 + (wnI >> 1) * 8192 + (wnI & 1) * 4096;
        u16* An = lsbase + ((t & 1) ^ 1) * 32768;
        u16* Bn = An + 16384;
        const bool pf = (t + 1 < NT);
        bf16x8 bq[4][2];

#pragma unroll
        for (int p = 0; p < 4; ++p) {
            // ---- phase entry: counted vmcnt + barrier ----
            if (p == 0)       asm volatile("s_waitcnt vmcnt(2)" ::: "memory");
            else if (p == 2) {
                if (pf)       asm volatile("s_waitcnt vmcnt(4)" ::: "memory");
                else          asm volatile("s_waitcnt vmcnt(0)" ::: "memory");
            }
            else if (p == 1)  asm volatile("s_waitcnt vmcnt(4)" ::: "memory");
            else              asm volatile("s_waitcnt vmcnt(6)" ::: "memory");
            __builtin_amdgcn_s_barrier();
            asm volatile("" ::: "memory");

            // ---- issue 2 next-tile stage loads (prefetch stays in flight) ----
            if (pf) {
                if (p == 0) {
                    GLD(sBk,                      Bn + 0     + wave * 512);
                    GLD(sBk + (size_t)64  * DIM,  Bn + 4096  + wave * 512);
                } else if (p == 1) {
                    GLD(sBk + (size_t)128 * DIM,  Bn + 8192  + wave * 512);
                    GLD(sBk + (size_t)192 * DIM,  Bn + 12288 + wave * 512);
                } else if (p == 2) {
                    GLD(sAk,                      An + 0     + wave * 512);
                    GLD(sAk + (size_t)128 * DIM,  An + 8192  + wave * 512);
                } else {
                    GLD(sAk + (size_t)64  * DIM,  An + 4096  + wave * 512);
                    GLD(sAk + (size_t)192 * DIM,  An + 12288 + wave * 512);
                }
            }

            // ---- ds_read fragments ----
            if (p == 0) {
#pragma unroll
                for (int j = 0; j < 4; ++j)
#pragma unroll
                    for (int s = 0; s < 2; ++s)
                        bq[j][s] = *(const bf16x8*)(Bc + s * 2048 + j * 512 + rdoff);
            }
            const int i0 = 2 * p, i1 = 2 * p + 1;
            bf16x8 a0[2], a1[2];
#pragma unroll
            for (int s = 0; s < 2; ++s) {
                a0[s] = *(const bf16x8*)(Ac + (i0 >> 2) * 4096 + s * 2048 + (i0 & 3) * 512 + rdoff);
                a1[s] = *(const bf16x8*)(Ac + (i1 >> 2) * 4096 + s * 2048 + (i1 & 3) * 512 + rdoff);
            }

            // ---- MFMA cluster (T5) ----
            __builtin_amdgcn_s_setprio(1);
#pragma unroll
            for (int s = 0; s < 2; ++s)
#pragma unroll
                for (int j = 0; j < 4; ++j) {
                    acc[i0][j] = __builtin_amdgcn_mfma_f32_16x16x32_bf16(a0[s], bq[j][s], acc[i0][j], 0, 0, 0);
                    acc[i1][j] = __builtin_amdgcn_mfma_f32_16x16x32_bf16(a1[s], bq[j][s], acc[i1][j], 0, 0, 0);
                }
            __builtin_amdgcn_s_setprio(0);
        }
        if (pf) { sAk += 64; sBk += 64; }
    }

    // ---------------- epilogue ----------------
    const int z = nt >> 2;                       // 0=Q 1=K 2=V
    const int nc = (nt & 3) * 256 + wnI * 64 + l15;  // col within z-matrix
    const float* bias = (z == 0) ? b0 : ((z == 1) ? b1 : b2);

    if (z < 2) {
        u16* Cb = QK + (size_t)z * B_ * SEQ * DIM;
        const int m00 = mt * 256 + wmH * 128 + quad * 4;
#pragma unroll
        for (int j = 0; j < 4; ++j) {
            float bv_ = bias[nc + j * 16];
#pragma unroll
            for (int i = 0; i < 8; ++i)
#pragma unroll
                for (int r = 0; r < 4; ++r)
                    Cb[(size_t)(m00 + i * 16 + r) * DIM + nc + j * 16] =
                        f2bf(acc[i][j][r] + bv_);
        }
        return;
    }

    // z == 2: V^T [d][s] via full-tile LDS transpose (token-XOR swizzle
    // kills the 512B-stride 16-way write conflict; XOR>=8-token units keeps
    // both the 8B writes and 16B reads contiguous).
    float addj[4];
#pragma unroll
    for (int j = 0; j < 4; ++j) addj[j] = bias[nc + j * 16];
    __syncthreads();                 // stage LDS fully consumed
#pragma unroll
    for (int i = 0; i < 8; ++i) {
        const int tb = wmH * 128 + i * 16 + quad * 4;    // token base
#pragma unroll
        for (int j = 0; j < 4; ++j) {
            const int d = wnI * 64 + j * 16 + l15;       // local dim 0..255
            ushort4 o;
            o.x = f2bf(acc[i][j][0] + addj[j]);
            o.y = f2bf(acc[i][j][1] + addj[j]);
            o.z = f2bf(acc[i][j][2] + addj[j]);
            o.w = f2bf(acc[i][j][3] + addj[j]);
            *(ushort4*)&sm.T[d * 256 + (tb ^ ((d & 7) << 3))] = o;
        }
    }
    __syncthreads();
    const int bI = mt >> 3;
    const int sbase = (mt & 7) * 256;
    u16* Vb = VtOut + (size_t)bI * DIM * SEQ + (size_t)(nt - 8) * 256 * SEQ + sbase;
#pragma unroll
    for (int k = 0; k < 16; ++k) {
        int idx = tid + 512 * k;                 // 0..8191
        int d = idx >> 5, sg = idx & 31;
        uint4 v = *(const uint4*)&sm.T[d * 256 + ((sg * 8) ^ ((d & 7) << 3))];
        *(uint4*)(Vb + (size_t)d * SEQ + sg * 8) = v;
    }
}

// ------- scores: S = Q @ K^T * scale (128x128, causal, heavy-first) ---------
__global__ __launch_bounds__(256, 3) void gemm_scores(
    const u16* __restrict__ Q, const u16* __restrict__ K, u16* __restrict__ S,
    float scale) {
    const int ym = gridDim.y - 1 - blockIdx.y;   // 0..15, heavy-first
    if ((int)blockIdx.x > ym) return;            // fully-masked tile

    __shared__ u16 lsA[128 * 64];   // 16 KB
    __shared__ u16 lsB[128 * 64];   // 16 KB
    const int tid = threadIdx.x;
    const int wave = tid >> 6, lane = tid & 63;
    const int quad = lane >> 4, l15 = lane & 15;
    const int wm = (wave >> 1) * 64, wn = (wave & 1) * 64;
    const int z = blockIdx.z;

    const u16* Ab = Q + (size_t)z * SEQ * DIM + (size_t)ym * 128 * DIM;
    const u16* Bb = K + (size_t)z * SEQ * DIM + (size_t)blockIdx.x * 128 * DIM;
    floatx4 acc[4][4];
    mainloop(Ab, Bb, DIM, DIM, DIM, lsA, lsB,
             tid, wave, quad, l15, wm, wn, acc);

    u16* Cb = S + (size_t)z * SEQ * SEQ;
    const int m0 = ym * 128 + wm + quad * 4;
    const int n0 = blockIdx.x * 128 + wn + l15;
#pragma unroll
    for (int j = 0; j < 4; j++)
#pragma unroll
        for (int i = 0; i < 4; i++)
#pragma unroll
            for (int r = 0; r < 4; r++)
                Cb[(size_t)(m0 + i * 16 + r) * SEQ + (n0 + j * 16)] = f2bf(acc[i][j][r] * scale);
}

// ------- context: out = P @ Vt^T (128x128, K limited, heavy-first) ----------
__global__ __launch_bounds__(256, 3) void gemm_pv(
    const u16* __restrict__ P, const u16* __restrict__ Vt, float* __restrict__ O) {
    const int ym = gridDim.y - 1 - blockIdx.y;   // 0..15, heavy-first
    __shared__ u16 lsA[128 * 64];
    __shared__ u16 lsB[128 * 64];
    const int tid = threadIdx.x;
    const int wave = tid >> 6, lane = tid & 63;
    const int quad = lane >> 4, l15 = lane & 15;
    const int wm = (wave >> 1) * 64, wn = (wave & 1) * 64;
    const int z = blockIdx.z;

    const u16* Ab = P + (size_t)z * SEQ * SEQ + (size_t)ym * 128 * SEQ;
    const u16* Bb = Vt + (size_t)z * DIM * SEQ + (size_t)blockIdx.x * 128 * SEQ;
    const int Kt = (ym + 1) * 128;  // keys needed by rows ym*128..+127
    floatx4 acc[4][4];
    mainloop(Ab, Bb, SEQ, SEQ, Kt, lsA, lsB,
             tid, wave, quad, l15, wm, wn, acc);

    float* Cf = O + (size_t)z * SEQ * DIM;
    const int m0 = ym * 128 + wm + quad * 4;
    const int n0 = blockIdx.x * 128 + wn + l15;
#pragma unroll
    for (int j = 0; j < 4; j++)
#pragma unroll
        for (int i = 0; i < 4; i++)
#pragma unroll
            for (int r = 0; r < 4; r++)
                Cf[(size_t)(m0 + i * 16 + r) * DIM + (n0 + j * 16)] = acc[i][j][r];
}

// -------- causal softmax: one row per block, register-resident, 1R+1W --------
__global__ __launch_bounds__(256) void softmax_causal(u16* __restrict__ S) {
    const int q = blockIdx.x, b = blockIdx.y, tid = threadIdx.x;
    u16* row = S + ((size_t)b * SEQ + q) * SEQ;
    const int L = q + 1;                    // valid keys
    const int Z = ((q >> 7) + 1) << 7;      // zero-fill bound = PV's K_eff
    const int k0 = tid * 8;
    __shared__ float redm[4], reds[4];

    uint4 rv = ((const uint4*)row)[tid];
    unsigned w[4] = {rv.x, rv.y, rv.z, rv.w};
    float f[8];
#pragma unroll
    for (int e = 0; e < 8; e++) {
        u16 h = (u16)((w[e >> 1] >> ((e & 1) * 16)) & 0xFFFFu);
        f[e] = (k0 + e < L) ? bf2f(h) : -3.0e38f;
    }
    float m = f[0];
#pragma unroll
    for (int e = 1; e < 8; e++) m = fmaxf(m, f[e]);
#pragma unroll
    for (int o = 32; o > 0; o >>= 1) m = fmaxf(m, __shfl_xor(m, o));
    if ((tid & 63) == 0) redm[tid >> 6] = m;
    __syncthreads();
    m = fmaxf(fmaxf(redm[0], redm[1]), fmaxf(redm[2], redm[3]));

    float p[8];
    float s = 0.f;
#pragma unroll
    for (int e = 0; e < 8; e++) {
        p[e] = (k0 + e < L) ? __expf(f[e] - m) : 0.f;
        s += p[e];
    }
#pragma unroll
    for (int o = 32; o > 0; o >>= 1) s += __shfl_xor(s, o);
    if ((tid & 63) == 0) reds[tid >> 6] = s;
    __syncthreads();
    s = reds[0] + reds[1] + reds[2] + reds[3];
    const float inv = 1.0f / s;

    if (k0 < Z) {
        unsigned o2[4];
#pragma unroll
        for (int e = 0; e < 4; e++) {
            unsigned lo = f2bf(p[2 * e] * inv);
            unsigned hi = f2bf(p[2 * e + 1] * inv);
            o2[e] = lo | (hi << 16);
        }
        uint4 ov = {o2[0], o2[1], o2[2], o2[3]};
        ((uint4*)row)[tid] = ov;
    }
}

extern "C" void kernel_launch(void* const* d_in, const int* in_sizes, int n_in,
                              void* d_out, int out_size, void* d_ws, size_t ws_size,
                              hipStream_t stream) {
    const float* x = (const float*)d_in[0];
    const float* Wq = (const float*)d_in[1];
    const float* bq = (const float*)d_in[2];
    const float* Wk = (const float*)d_in[3];
    const float* bk = (const float*)d_in[4];
    const float* Wv = (const float*)d_in[5];
    const float* bv = (const float*)d_in[6];
    float* out = (float*)d_out;

    char* ws = (char*)d_ws;
    const size_t MB = 1024ull * 1024ull;
    // layout: [0,32MB) early: xb(16MB)+Wt(6MB); late: S/P bf16 (32MB)
    //         [32,48) Q bf16 ; [48,64) K bf16 ; [64,80) Vt bf16 [d][s] per batch
    u16* S = (u16*)ws;
    u16* xb = (u16*)ws;
    u16* Wt = (u16*)(ws + 16 * MB);
    u16* QK = (u16*)(ws + 32 * MB);
    u16* Vt = (u16*)(ws + 64 * MB);
    const size_t MAT = (size_t)B_ * SEQ * DIM;  // 8M elements
    u16* Q = QK;
    u16* Km = QK + MAT;

    const float scale = 0.03125f;  // 1/sqrt(1024)

    convert_x<<<8192, 256, 0, stream>>>((const float4*)x, (ushort4*)xb);
    transpose_w<<<dim3(16, 16, 3), dim3(32, 8), 0, stream>>>(Wq, Wk, Wv, Wt);
    gemm_qkv256<<<dim3(384), dim3(512), 0, stream>>>(xb, Wt, QK, bq, bk, bv, Vt);
    gemm_scores<<<dim3(16, 16, 4), 256, 0, stream>>>(Q, Km, S, scale);
    softmax_causal<<<dim3(SEQ, B_), 256, 0, stream>>>(S);
    gemm_pv<<<dim3(8, 16, 4), 256, 0, stream>>>(S, Vt, out);
}